// Round 3
// baseline (641.311 us; speedup 1.0000x reference)
//
#include <hip/hip_runtime.h>
#include <stdint.h>

typedef unsigned short u16;
typedef unsigned int u32;
typedef __bf16 bf16x8 __attribute__((ext_vector_type(8)));
typedef float f32x4 __attribute__((ext_vector_type(4)));

#define SC_Q 0.17677669529663687f  // 1/sqrt(32), folded into wq/bq

__device__ __forceinline__ u16 f2b(float f) {
  u32 u = __float_as_uint(f);
  u = (u + 0x7fffu + ((u >> 16) & 1u)) >> 16;
  return (u16)u;
}
__device__ __forceinline__ float b2f(u16 h) {
  return __uint_as_float(((u32)h) << 16);
}
__device__ __forceinline__ u32 pack2(float a, float b) {
  return (u32)f2b(a) | ((u32)f2b(b) << 16);
}
__device__ __forceinline__ void gload_lds16(const u16* g, u16* l) {
  __builtin_amdgcn_global_load_lds(
      (const __attribute__((address_space(1))) void*)g,
      (__attribute__((address_space(3))) void*)l, 16, 0, 0);
}

// ---------------- weight prep: fp32 -> bf16, q-rows scaled --------------
__global__ void prep_weights(const float* __restrict__ wil, const float* __restrict__ wol,
                             const float* __restrict__ wis, const float* __restrict__ wos,
                             const float* __restrict__ w1, const float* __restrict__ w2,
                             u16* __restrict__ out) {
  int idx = (blockIdx.x * 256 + threadIdx.x) * 4;
  u16 r[4];
#pragma unroll
  for (int j = 0; j < 4; ++j) {
    int i = idx + j;
    float x;
    if (i < 196608)      { x = wil[i]; if (i < 65536) x *= SC_Q; }
    else if (i < 262144) { x = wol[i - 196608]; }
    else if (i < 458752) { int k = i - 262144; x = wis[k]; if (k < 65536) x *= SC_Q; }
    else if (i < 524288) { x = wos[i - 458752]; }
    else if (i < 786432) { x = w1[i - 524288]; }
    else                 { x = w2[i - 786432]; }
    r[j] = f2b(x);
  }
  *(uint2*)(out + idx) = make_uint2((u32)r[0] | ((u32)r[1] << 16),
                                    (u32)r[2] | ((u32)r[3] << 16));
}

__global__ void prep_bias(const float* __restrict__ bil, const float* __restrict__ bis,
                          float* __restrict__ out) {
  int i = blockIdx.x * 256 + threadIdx.x;
  if (i < 768)       out[i] = bil[i] * (i < 256 ? SC_Q : 1.0f);
  else if (i < 1536) { int k = i - 768; out[i] = bis[k] * (k < 256 ? SC_Q : 1.0f); }
}

// ------------- gather: src -> long layout, A1=x+pos (bf16), A2=x --------
__global__ void gather_long(const float* __restrict__ src, const float* __restrict__ pos,
                            u16* __restrict__ A1, u16* __restrict__ A2) {
  int gid = blockIdx.x * 256 + threadIdx.x;
  int u = gid >> 6, lane = gid & 63;
  int l = u >> 10, t = u & 1023;
  int bh = l >> 3, bw = l & 7;
  int b = t >> 7, h = (t >> 3) & 15, w = t & 7;
  int n = bh * 1024 + h * 64 + bw * 8 + w;
  float4 s4 = ((const float4*)(src + ((size_t)b * 8192 + n) * 256))[lane];
  float4 p4 = ((const float4*)(pos + (size_t)n * 256))[lane];
  ((uint2*)(A1 + (size_t)u * 256))[lane] =
      make_uint2(pack2(s4.x + p4.x, s4.y + p4.y), pack2(s4.z + p4.z, s4.w + p4.w));
  ((uint2*)(A2 + (size_t)u * 256))[lane] =
      make_uint2(pack2(s4.x, s4.y), pack2(s4.z, s4.w));
}

// ------ gather: v_long (bf16) -> short layout; A1s = v+ps, A2s = v ------
__global__ void gather_short(const u16* __restrict__ VL, const float* __restrict__ pos,
                             u16* __restrict__ A1s, u16* __restrict__ A2s) {
  int gid = blockIdx.x * 256 + threadIdx.x;
  int u2 = gid >> 6, lane = gid & 63;
  int s = u2 >> 9, r = u2 & 511;
  int hq = s >> 3, wq = s & 7;
  int b = r >> 6, bh = (r >> 3) & 7, bw = r & 7;
  int u = b * 8192 + bh * 1024 + hq * 64 + bw * 8 + wq;
  int l = u >> 10, t = u & 1023;
  int pbh = l >> 3, pbw = l & 7, ph = (t >> 3) & 15, pw = t & 7;
  int np = pbh * 1024 + ph * 64 + pbw * 8 + pw;
  uint2 vv = ((const uint2*)(VL + (size_t)u * 256))[lane];
  float4 p4 = ((const float4*)(pos + (size_t)np * 256))[lane];
  float v0 = b2f((u16)(vv.x & 0xffff)), v1 = b2f((u16)(vv.x >> 16));
  float v2 = b2f((u16)(vv.y & 0xffff)), v3 = b2f((u16)(vv.y >> 16));
  ((uint2*)(A1s + (size_t)u2 * 256))[lane] =
      make_uint2(pack2(v0 + p4.x, v1 + p4.y), pack2(v2 + p4.z, v3 + p4.w));
  ((uint2*)(A2s + (size_t)u2 * 256))[lane] = vv;
}

// -------- m97-style bf16 MFMA GEMM: C[M,N] = A[M,K] @ W[N,K]^T + bias ---
// 128x128 tile, 4 waves (each 64x64), BK=32, global_load_lds width-16.
// blockIdx.x = m-tile (fastest -> same-m group spans XCDs? no: same-m blocks
// are gridDim.x apart, gridDim.x=512 multiple of 8 -> same XCD, L2 reuse).
// MFMA roles swapped (A-operand = W rows): D rows = n, cols = m -> per lane
// 4 consecutive n per token -> packed dwordx2 stores.
__global__ __launch_bounds__(256) void gemm128(
    const u16* __restrict__ A1, const u16* __restrict__ A2, int n_split,
    const u16* __restrict__ W, const float* __restrict__ bias,
    u16* __restrict__ C, int N, int K, int relu) {
  __shared__ __align__(16) u16 As[128 * 32];
  __shared__ __align__(16) u16 Bs[128 * 32];
  int m0 = blockIdx.x * 128, n0 = blockIdx.y * 128;
  const u16* A = (n0 < n_split) ? A1 : A2;
  int tid = threadIdx.x;
  int lane = tid & 63, wv = tid >> 6;
  int row = tid >> 2, seg = tid & 3;
  int wr = wv & 1, wc = wv >> 1;
  int r15 = lane & 15, q = lane >> 4;
  f32x4 acc[4][4];  // [j: n-tile][i: m-tile]
#pragma unroll
  for (int j = 0; j < 4; ++j)
#pragma unroll
    for (int i = 0; i < 4; ++i)
#pragma unroll
      for (int r = 0; r < 4; ++r) acc[j][i][r] = 0.f;

  const u16* ag0 = A + (size_t)(m0 + row) * K + seg * 8;
  const u16* ag1 = A + (size_t)(m0 + 64 + row) * K + seg * 8;
  const u16* bg0 = W + (size_t)(n0 + row) * K + seg * 8;
  const u16* bg1 = W + (size_t)(n0 + 64 + row) * K + seg * 8;
  u16* lA0 = As + wv * 512;
  u16* lA1 = As + wv * 512 + 2048;
  u16* lB0 = Bs + wv * 512;
  u16* lB1 = Bs + wv * 512 + 2048;

  for (int k0 = 0; k0 < K; k0 += 32) {
    gload_lds16(ag0 + k0, lA0);
    gload_lds16(ag1 + k0, lA1);
    gload_lds16(bg0 + k0, lB0);
    gload_lds16(bg1 + k0, lB1);
    __syncthreads();
    bf16x8 wf[4], xf[4];
#pragma unroll
    for (int j = 0; j < 4; ++j)
      wf[j] = *(const bf16x8*)&Bs[(wc * 64 + j * 16 + r15) * 32 + q * 8];
#pragma unroll
    for (int i = 0; i < 4; ++i)
      xf[i] = *(const bf16x8*)&As[(wr * 64 + i * 16 + r15) * 32 + q * 8];
#pragma unroll
    for (int j = 0; j < 4; ++j)
#pragma unroll
      for (int i = 0; i < 4; ++i)
        acc[j][i] = __builtin_amdgcn_mfma_f32_16x16x32_bf16(wf[j], xf[i], acc[j][i], 0, 0, 0);
    __syncthreads();
  }
  // D (A=W): row = n-local = q*4 + r, col = m-local = lane&15
#pragma unroll
  for (int j = 0; j < 4; ++j) {
    int nb = n0 + wc * 64 + j * 16 + q * 4;
    float4 b4 = *(const float4*)(bias + nb);
#pragma unroll
    for (int i = 0; i < 4; ++i) {
      int m = m0 + wr * 64 + i * 16 + r15;
      float v0 = acc[j][i][0] + b4.x;
      float v1 = acc[j][i][1] + b4.y;
      float v2 = acc[j][i][2] + b4.z;
      float v3 = acc[j][i][3] + b4.w;
      if (relu) {
        v0 = fmaxf(v0, 0.f); v1 = fmaxf(v1, 0.f);
        v2 = fmaxf(v2, 0.f); v3 = fmaxf(v3, 0.f);
      }
      *(uint2*)(C + (size_t)m * N + nb) = make_uint2(pack2(v0, v1), pack2(v2, v3));
    }
  }
}

// ------------- MFMA attention: one block per (t, head) ------------------
template <int L, int Bt>
__global__ __launch_bounds__(4 * L) void attn_mfma(const u16* __restrict__ qkv,
                                                   u16* __restrict__ O) {
  constexpr int L16 = L / 16, LP = L + 8;
  __shared__ __align__(16) u16 Ks[L * 40];
  __shared__ __align__(16) u16 VT[32 * LP];
  __shared__ __align__(16) u16 Ps[L16 * 16 * LP];
  int p = blockIdx.x, t = p >> 3, head = p & 7;
  int tid = threadIdx.x;
  {
    int r = tid >> 2, seg = tid & 3;
    const u16* base = qkv + ((size_t)r * Bt + t) * 768 + head * 32 + seg * 8;
    uint4 kvv = *(const uint4*)(base + 256);
    *(uint4*)&Ks[r * 40 + seg * 8] = kvv;
    uint4 vv = *(const uint4*)(base + 512);
    u32 wds[4] = {vv.x, vv.y, vv.z, vv.w};
#pragma unroll
    for (int e = 0; e < 4; ++e) {
      VT[(seg * 8 + e * 2 + 0) * LP + r] = (u16)(wds[e] & 0xffffu);
      VT[(seg * 8 + e * 2 + 1) * LP + r] = (u16)(wds[e] >> 16);
    }
  }
  int lane = tid & 63, w = tid >> 6;
  int r15 = lane & 15, q = lane >> 4;
  bf16x8 af = *(const bf16x8*)(qkv + ((size_t)(w * 16 + r15) * Bt + t) * 768 + head * 32 + q * 8);
  __syncthreads();
  f32x4 z = {0.f, 0.f, 0.f, 0.f};
  f32x4 s[L16];
#pragma unroll
  for (int jt = 0; jt < L16; ++jt) {
    bf16x8 bf = *(const bf16x8*)&Ks[(jt * 16 + r15) * 40 + q * 8];
    s[jt] = __builtin_amdgcn_mfma_f32_16x16x32_bf16(af, bf, z, 0, 0, 0);
  }
  float inv[4];
#pragma unroll
  for (int r = 0; r < 4; ++r) {
    float mx = s[0][r];
#pragma unroll
    for (int jt = 1; jt < L16; ++jt) mx = fmaxf(mx, s[jt][r]);
    mx = fmaxf(mx, __shfl_xor(mx, 1));
    mx = fmaxf(mx, __shfl_xor(mx, 2));
    mx = fmaxf(mx, __shfl_xor(mx, 4));
    mx = fmaxf(mx, __shfl_xor(mx, 8));
    float sum = 0.f;
#pragma unroll
    for (int jt = 0; jt < L16; ++jt) {
      float pe = __expf(s[jt][r] - mx);
      s[jt][r] = pe;
      sum += pe;
    }
    sum += __shfl_xor(sum, 1);
    sum += __shfl_xor(sum, 2);
    sum += __shfl_xor(sum, 4);
    sum += __shfl_xor(sum, 8);
    inv[r] = 1.f / sum;
  }
  int pbase = w * 16 * LP;
#pragma unroll
  for (int jt = 0; jt < L16; ++jt)
#pragma unroll
    for (int r = 0; r < 4; ++r)
      Ps[pbase + (q * 4 + r) * LP + jt * 16 + r15] = f2b(s[jt][r]);
  __syncthreads();
  f32x4 o[2] = {z, z};
#pragma unroll
  for (int kt = 0; kt < L / 32; ++kt) {
    bf16x8 ap = *(const bf16x8*)&Ps[pbase + r15 * LP + kt * 32 + q * 8];
#pragma unroll
    for (int nt = 0; nt < 2; ++nt) {
      bf16x8 bv = *(const bf16x8*)&VT[(nt * 16 + r15) * LP + kt * 32 + q * 8];
      o[nt] = __builtin_amdgcn_mfma_f32_16x16x32_bf16(ap, bv, o[nt], 0, 0, 0);
    }
  }
#pragma unroll
  for (int nt = 0; nt < 2; ++nt)
#pragma unroll
    for (int r = 0; r < 4; ++r) {
      float v = o[nt][r] * inv[r];
      size_t addr = ((size_t)(w * 16 + q * 4 + r) * Bt + t) * 256 + head * 32 + nt * 16 + r15;
      O[addr] = f2b(v);
    }
}

// ------- LN1: x = LN(src + src2_short[permuted]), one wave per token ----
__global__ void ln1(const float* __restrict__ src, const u16* __restrict__ s2b,
                    const float* __restrict__ g, const float* __restrict__ be,
                    u16* __restrict__ xln) {
  int gid = blockIdx.x * 256 + threadIdx.x;
  int u2 = gid >> 6, lane = gid & 63;
  int s = u2 >> 9, r = u2 & 511;
  int hq = s >> 3, wq = s & 7;
  int b = r >> 6, bh = (r >> 3) & 7, bw = r & 7;
  int n2 = hq * 512 + bh * 64 + wq * 8 + bw;
  size_t urow = (size_t)b * 8192 + n2;
  float4 a = ((const float4*)(src + urow * 256))[lane];
  uint2 vv = ((const uint2*)(s2b + (size_t)u2 * 256))[lane];
  float v0 = a.x + b2f((u16)(vv.x & 0xffff));
  float v1 = a.y + b2f((u16)(vv.x >> 16));
  float v2 = a.z + b2f((u16)(vv.y & 0xffff));
  float v3 = a.w + b2f((u16)(vv.y >> 16));
  float s1 = v0 + v1 + v2 + v3;
  float sq = v0*v0 + v1*v1 + v2*v2 + v3*v3;
#pragma unroll
  for (int off = 32; off >= 1; off >>= 1) {
    s1 += __shfl_xor(s1, off, 64);
    sq += __shfl_xor(sq, off, 64);
  }
  float mu = s1 * (1.f / 256.f);
  float var = sq * (1.f / 256.f) - mu * mu;
  float rstd = rsqrtf(var + 1e-5f);
  float4 g4 = ((const float4*)g)[lane];
  float4 e4 = ((const float4*)be)[lane];
  float y0 = (v0 - mu) * rstd * g4.x + e4.x;
  float y1 = (v1 - mu) * rstd * g4.y + e4.y;
  float y2 = (v2 - mu) * rstd * g4.z + e4.z;
  float y3 = (v3 - mu) * rstd * g4.w + e4.w;
  ((uint2*)(xln + urow * 256))[lane] = make_uint2(pack2(y0, y1), pack2(y2, y3));
}

// --- LN2 + final transposed write: out[b, c*8192 + n] = LN(x + ff)[b,n,c]
__global__ __launch_bounds__(256) void ln2t(const u16* __restrict__ ff, const u16* __restrict__ xln,
                                            const float* __restrict__ g, const float* __restrict__ be,
                                            float* __restrict__ out) {
  __shared__ u16 tileT[256][65];
  __shared__ float ps1[64][4];
  __shared__ float ps2[64][4];
  __shared__ float mu_s[64], rs_s[64];
  int b = blockIdx.x >> 7;
  int n0 = (blockIdx.x & 127) * 64;
  int tid = threadIdx.x;
  int i = tid >> 2, ch = tid & 3;
  size_t u = (size_t)b * 8192 + n0 + i;
  const uint4* fr = (const uint4*)(ff + u * 256 + ch * 64);
  const uint4* xr = (const uint4*)(xln + u * 256 + ch * 64);
  float s1 = 0.f, sq = 0.f;
#pragma unroll
  for (int j = 0; j < 8; ++j) {
    uint4 fv = fr[j];
    uint4 xv = xr[j];
    u32 fw[4] = {fv.x, fv.y, fv.z, fv.w};
    u32 xw[4] = {xv.x, xv.y, xv.z, xv.w};
    int cbase = ch * 64 + j * 8;
#pragma unroll
    for (int e = 0; e < 4; ++e) {
      float f0 = __uint_as_float(fw[e] << 16) + __uint_as_float(xw[e] << 16);
      float f1 = __uint_as_float(fw[e] & 0xffff0000u) + __uint_as_float(xw[e] & 0xffff0000u);
      s1 += f0 + f1; sq += f0 * f0 + f1 * f1;
      tileT[cbase + e * 2 + 0][i] = f2b(f0);
      tileT[cbase + e * 2 + 1][i] = f2b(f1);
    }
  }
  ps1[i][ch] = s1; ps2[i][ch] = sq;
  __syncthreads();
  if (tid < 64) {
    float a1 = ps1[tid][0] + ps1[tid][1] + ps1[tid][2] + ps1[tid][3];
    float a2 = ps2[tid][0] + ps2[tid][1] + ps2[tid][2] + ps2[tid][3];
    float mu = a1 * (1.f / 256.f);
    float var = a2 * (1.f / 256.f) - mu * mu;
    mu_s[tid] = mu;
    rs_s[tid] = rsqrtf(var + 1e-5f);
  }
  __syncthreads();
  int ii = tid & 63, cq = tid >> 6;
  float mu = mu_s[ii], rs = rs_s[ii];
  float* ob = out + (size_t)b * 2097152 + n0 + ii;
#pragma unroll 4
  for (int pass = 0; pass < 64; ++pass) {
    int c = pass * 4 + cq;
    float val = b2f(tileT[c][ii]);
    float y = (val - mu) * rs * g[c] + be[c];
    ob[(size_t)c * 8192] = y;
  }
}

extern "C" void kernel_launch(void* const* d_in, const int* in_sizes, int n_in,
                              void* d_out, int out_size, void* d_ws, size_t ws_size,
                              hipStream_t stream) {
  (void)in_sizes; (void)n_in; (void)out_size; (void)ws_size;
  const float* src = (const float*)d_in[0];
  const float* pos = (const float*)d_in[1];
  const float* wil = (const float*)d_in[2];
  const float* bil = (const float*)d_in[3];
  const float* wol = (const float*)d_in[4];
  const float* bol = (const float*)d_in[5];
  const float* wis = (const float*)d_in[6];
  const float* bis = (const float*)d_in[7];
  const float* wos = (const float*)d_in[8];
  const float* bos = (const float*)d_in[9];
  const float* w1  = (const float*)d_in[10];
  const float* b1  = (const float*)d_in[11];
  const float* w2  = (const float*)d_in[12];
  const float* b2  = (const float*)d_in[13];
  const float* g1  = (const float*)d_in[14];
  const float* be1 = (const float*)d_in[15];
  const float* g2  = (const float*)d_in[16];
  const float* be2 = (const float*)d_in[17];

  char* ws = (char*)d_ws;
  u16* WB   = (u16*)ws;                       // [0,2M): bf16 weights
  float* BS = (float*)(ws + (2ull << 20));    // scaled b_in copies
  u16* QKV  = (u16*)(ws + (4ull << 20));      // [4M,100M): qkv
  u16* R1   = (u16*)(ws + (100ull << 20));    // 32MB
  u16* R2   = (u16*)(ws + (132ull << 20));    // 32MB
  u16* R3   = (u16*)(ws + (164ull << 20));    // 32MB
  u16* H    = QKV;                            // 128MB hidden, spans QKV+R1

  u16* wl_in  = WB;
  u16* wl_out = WB + 196608;
  u16* ws_in  = WB + 262144;
  u16* ws_out = WB + 458752;
  u16* w1b    = WB + 524288;
  u16* w2b    = WB + 786432;
  float* bsl = BS;
  float* bss = BS + 768;

  prep_weights<<<1024, 256, 0, stream>>>(wil, wol, wis, wos, w1, w2, WB);
  prep_bias<<<6, 256, 0, stream>>>(bil, bis, BS);
  // long stage
  gather_long<<<16384, 256, 0, stream>>>(src, pos, R1, R2);
  gemm128<<<dim3(512, 6), 256, 0, stream>>>(R1, R2, 512, wl_in, bsl, QKV, 768, 256, 0);
  attn_mfma<64, 1024><<<8192, 256, 0, stream>>>(QKV, R3);
  gemm128<<<dim3(512, 2), 256, 0, stream>>>(R3, R3, 1 << 30, wl_out, bol, R1, 256, 256, 0);
  // short stage
  gather_short<<<16384, 256, 0, stream>>>(R1, pos, R2, R3);
  gemm128<<<dim3(512, 6), 256, 0, stream>>>(R2, R3, 512, ws_in, bss, QKV, 768, 256, 0);
  attn_mfma<128, 512><<<4096, 512, 0, stream>>>(QKV, R1);
  gemm128<<<dim3(512, 2), 256, 0, stream>>>(R1, R1, 1 << 30, ws_out, bos, R2, 256, 256, 0);
  // residual + LN1
  ln1<<<16384, 256, 0, stream>>>(src, R2, g1, be1, R3);
  // FFN
  gemm128<<<dim3(512, 8), 256, 0, stream>>>(R3, R3, 1 << 30, w1b, b1, H, 1024, 256, 1);
  gemm128<<<dim3(512, 2), 256, 0, stream>>>(H, H, 1 << 30, w2b, b2, R2, 256, 1024, 0);
  // residual + LN2 + transposed output
  ln2t<<<1024, 256, 0, stream>>>(R2, R3, g2, be2, (float*)d_out);
}

// Round 5
// 558.472 us; speedup vs baseline: 1.1483x; 1.1483x over previous
//
#include <hip/hip_runtime.h>
#include <stdint.h>

typedef unsigned short u16;
typedef unsigned int u32;
typedef __bf16 bf16x8 __attribute__((ext_vector_type(8)));
typedef float f32x4 __attribute__((ext_vector_type(4)));

#define SC_Q 0.17677669529663687f  // 1/sqrt(32), folded into wq/bq

__device__ __forceinline__ u16 f2b(float f) {
  u32 u = __float_as_uint(f);
  u = (u + 0x7fffu + ((u >> 16) & 1u)) >> 16;
  return (u16)u;
}
__device__ __forceinline__ float b2f(u16 h) {
  return __uint_as_float(((u32)h) << 16);
}
__device__ __forceinline__ u32 pack2(float a, float b) {
  return (u32)f2b(a) | ((u32)f2b(b) << 16);
}
__device__ __forceinline__ void gload_lds16(const u16* g, u16* l) {
  __builtin_amdgcn_global_load_lds(
      (const __attribute__((address_space(1))) void*)g,
      (__attribute__((address_space(3))) void*)l, 16, 0, 0);
}

// ---------------- weight prep: fp32 -> bf16, q-rows scaled --------------
__global__ void prep_weights(const float* __restrict__ wil, const float* __restrict__ wol,
                             const float* __restrict__ wis, const float* __restrict__ wos,
                             const float* __restrict__ w1, const float* __restrict__ w2,
                             u16* __restrict__ out) {
  int idx = (blockIdx.x * 256 + threadIdx.x) * 4;
  u16 r[4];
#pragma unroll
  for (int j = 0; j < 4; ++j) {
    int i = idx + j;
    float x;
    if (i < 196608)      { x = wil[i]; if (i < 65536) x *= SC_Q; }
    else if (i < 262144) { x = wol[i - 196608]; }
    else if (i < 458752) { int k = i - 262144; x = wis[k]; if (k < 65536) x *= SC_Q; }
    else if (i < 524288) { x = wos[i - 458752]; }
    else if (i < 786432) { x = w1[i - 524288]; }
    else                 { x = w2[i - 786432]; }
    r[j] = f2b(x);
  }
  *(uint2*)(out + idx) = make_uint2((u32)r[0] | ((u32)r[1] << 16),
                                    (u32)r[2] | ((u32)r[3] << 16));
}

__global__ void prep_bias(const float* __restrict__ bil, const float* __restrict__ bis,
                          float* __restrict__ out) {
  int i = blockIdx.x * 256 + threadIdx.x;
  if (i < 768)       out[i] = bil[i] * (i < 256 ? SC_Q : 1.0f);
  else if (i < 1536) { int k = i - 768; out[i] = bis[k] * (k < 256 ? SC_Q : 1.0f); }
}

// ------------- gather: src -> long layout, A1=x+pos (bf16), A2=x --------
__global__ void gather_long(const float* __restrict__ src, const float* __restrict__ pos,
                            u16* __restrict__ A1, u16* __restrict__ A2) {
  int gid = blockIdx.x * 256 + threadIdx.x;
  int u = gid >> 6, lane = gid & 63;
  int l = u >> 10, t = u & 1023;
  int bh = l >> 3, bw = l & 7;
  int b = t >> 7, h = (t >> 3) & 15, w = t & 7;
  int n = bh * 1024 + h * 64 + bw * 8 + w;
  float4 s4 = ((const float4*)(src + ((size_t)b * 8192 + n) * 256))[lane];
  float4 p4 = ((const float4*)(pos + (size_t)n * 256))[lane];
  ((uint2*)(A1 + (size_t)u * 256))[lane] =
      make_uint2(pack2(s4.x + p4.x, s4.y + p4.y), pack2(s4.z + p4.z, s4.w + p4.w));
  ((uint2*)(A2 + (size_t)u * 256))[lane] =
      make_uint2(pack2(s4.x, s4.y), pack2(s4.z, s4.w));
}

// ------ gather: v_long (bf16) -> short layout; A1s = v+ps, A2s = v ------
__global__ void gather_short(const u16* __restrict__ VL, const float* __restrict__ pos,
                             u16* __restrict__ A1s, u16* __restrict__ A2s) {
  int gid = blockIdx.x * 256 + threadIdx.x;
  int u2 = gid >> 6, lane = gid & 63;
  int s = u2 >> 9, r = u2 & 511;
  int hq = s >> 3, wq = s & 7;
  int b = r >> 6, bh = (r >> 3) & 7, bw = r & 7;
  int u = b * 8192 + bh * 1024 + hq * 64 + bw * 8 + wq;
  int l = u >> 10, t = u & 1023;
  int pbh = l >> 3, pbw = l & 7, ph = (t >> 3) & 15, pw = t & 7;
  int np = pbh * 1024 + ph * 64 + pbw * 8 + pw;
  uint2 vv = ((const uint2*)(VL + (size_t)u * 256))[lane];
  float4 p4 = ((const float4*)(pos + (size_t)np * 256))[lane];
  float v0 = b2f((u16)(vv.x & 0xffff)), v1 = b2f((u16)(vv.x >> 16));
  float v2 = b2f((u16)(vv.y & 0xffff)), v3 = b2f((u16)(vv.y >> 16));
  ((uint2*)(A1s + (size_t)u2 * 256))[lane] =
      make_uint2(pack2(v0 + p4.x, v1 + p4.y), pack2(v2 + p4.z, v3 + p4.w));
  ((uint2*)(A2s + (size_t)u2 * 256))[lane] = vv;
}

// -------- bf16 MFMA GEMM: C[M,N] = A[M,K] @ W[N,K]^T + bias ------------
// 128x128 tile, 4 waves (each 64x64), BK=64, global_load_lds width-16.
// 1D grid swizzle: XCD = m%8; n-siblings of one m-tile consecutive within
// an XCD -> A tile L2-hot across its NT n-blocks.
// LDS XOR-swizzle via permuted GLOBAL source columns (LDS dest must stay
// lane-ordered for global_load_lds): LDS[row][c8] = G[row][c8 ^ (row&7)].
// Fragment read: chunk = (kk*4 + q) ^ (row&7)  [row&7 == r15&7].
template <int NT>
__global__ __launch_bounds__(256) void gemm128(
    const u16* __restrict__ A1, const u16* __restrict__ A2, int n_split,
    const u16* __restrict__ W, const float* __restrict__ bias,
    u16* __restrict__ C, int N, int K, int relu) {
  __shared__ __align__(16) u16 As[128 * 64];
  __shared__ __align__(16) u16 Bs[128 * 64];
  int L = blockIdx.x;
  int mt = ((L >> 3) / NT) * 8 + (L & 7);
  int nt = (L >> 3) % NT;
  int m0 = mt * 128, n0 = nt * 128;
  const u16* A = (n0 < n_split) ? A1 : A2;
  int tid = threadIdx.x;
  int lane = tid & 63, wv = tid >> 6;
  int wr = wv & 1, wc = wv >> 1;
  int r15 = lane & 15, q = lane >> 4;
  int rowt = tid >> 3;                    // 0..31 (staging row, +g*32)
  int pc = (tid & 7) ^ (rowt & 7);        // permuted source col-chunk
  f32x4 acc[4][4];
#pragma unroll
  for (int i = 0; i < 4; ++i)
#pragma unroll
    for (int j = 0; j < 4; ++j)
#pragma unroll
      for (int r = 0; r < 4; ++r) acc[i][j][r] = 0.f;

  const u16* ag = A + (size_t)(m0 + rowt) * K + pc * 8;
  const u16* bg = W + (size_t)(n0 + rowt) * K + pc * 8;
  int xs = r15 & 7;                       // fragment-read XOR (chunk units)

  for (int k0 = 0; k0 < K; k0 += 64) {
#pragma unroll
    for (int g = 0; g < 4; ++g) {
      // LDS base wave-uniform; HW adds lane*16B. chunk = g*256 + wv*64 + lane
      gload_lds16(ag + (size_t)(g * 32) * K + k0, As + g * 2048 + wv * 512);
      gload_lds16(bg + (size_t)(g * 32) * K + k0, Bs + g * 2048 + wv * 512);
    }
    __syncthreads();
#pragma unroll
    for (int kk = 0; kk < 2; ++kk) {
      int co = ((kk * 4 + q) ^ xs) * 8;   // element offset within row
      bf16x8 af[4], bf[4];
#pragma unroll
      for (int i = 0; i < 4; ++i) {
        int row = wr * 64 + i * 16 + r15;
        af[i] = *(const bf16x8*)&As[row * 64 + co];
      }
#pragma unroll
      for (int j = 0; j < 4; ++j) {
        int row = wc * 64 + j * 16 + r15;
        bf[j] = *(const bf16x8*)&Bs[row * 64 + co];
      }
#pragma unroll
      for (int i = 0; i < 4; ++i)
#pragma unroll
        for (int j = 0; j < 4; ++j)
          acc[i][j] = __builtin_amdgcn_mfma_f32_16x16x32_bf16(af[i], bf[j], acc[i][j], 0, 0, 0);
    }
    __syncthreads();
  }
  // D: row(m) = q*4 + r, col(n) = lane&15
#pragma unroll
  for (int j = 0; j < 4; ++j) {
    int n = n0 + wc * 64 + j * 16 + r15;
    float bb = bias[n];
#pragma unroll
    for (int i = 0; i < 4; ++i)
#pragma unroll
      for (int r = 0; r < 4; ++r) {
        int m = m0 + wr * 64 + i * 16 + q * 4 + r;
        float v = acc[i][j][r] + bb;
        if (relu) v = fmaxf(v, 0.f);
        C[(size_t)m * N + n] = f2b(v);
      }
  }
}

// ------------- MFMA attention: one block per (t, head) ------------------
template <int L, int Bt>
__global__ __launch_bounds__(4 * L) void attn_mfma(const u16* __restrict__ qkv,
                                                   u16* __restrict__ O) {
  constexpr int L16 = L / 16, LP = L + 8;
  __shared__ __align__(16) u16 Ks[L * 40];
  __shared__ __align__(16) u16 VT[32 * LP];
  __shared__ __align__(16) u16 Ps[L16 * 16 * LP];
  int p = blockIdx.x, t = p >> 3, head = p & 7;
  int tid = threadIdx.x;
  {
    int r = tid >> 2, seg = tid & 3;
    const u16* base = qkv + ((size_t)r * Bt + t) * 768 + head * 32 + seg * 8;
    uint4 kvv = *(const uint4*)(base + 256);
    *(uint4*)&Ks[r * 40 + seg * 8] = kvv;
    uint4 vv = *(const uint4*)(base + 512);
    u32 wds[4] = {vv.x, vv.y, vv.z, vv.w};
#pragma unroll
    for (int e = 0; e < 4; ++e) {
      VT[(seg * 8 + e * 2 + 0) * LP + r] = (u16)(wds[e] & 0xffffu);
      VT[(seg * 8 + e * 2 + 1) * LP + r] = (u16)(wds[e] >> 16);
    }
  }
  int lane = tid & 63, w = tid >> 6;
  int r15 = lane & 15, q = lane >> 4;
  bf16x8 af = *(const bf16x8*)(qkv + ((size_t)(w * 16 + r15) * Bt + t) * 768 + head * 32 + q * 8);
  __syncthreads();
  f32x4 z = {0.f, 0.f, 0.f, 0.f};
  f32x4 s[L16];
#pragma unroll
  for (int jt = 0; jt < L16; ++jt) {
    bf16x8 bf = *(const bf16x8*)&Ks[(jt * 16 + r15) * 40 + q * 8];
    s[jt] = __builtin_amdgcn_mfma_f32_16x16x32_bf16(af, bf, z, 0, 0, 0);
  }
  float inv[4];
#pragma unroll
  for (int r = 0; r < 4; ++r) {
    float mx = s[0][r];
#pragma unroll
    for (int jt = 1; jt < L16; ++jt) mx = fmaxf(mx, s[jt][r]);
    mx = fmaxf(mx, __shfl_xor(mx, 1));
    mx = fmaxf(mx, __shfl_xor(mx, 2));
    mx = fmaxf(mx, __shfl_xor(mx, 4));
    mx = fmaxf(mx, __shfl_xor(mx, 8));
    float sum = 0.f;
#pragma unroll
    for (int jt = 0; jt < L16; ++jt) {
      float pe = __expf(s[jt][r] - mx);
      s[jt][r] = pe;
      sum += pe;
    }
    sum += __shfl_xor(sum, 1);
    sum += __shfl_xor(sum, 2);
    sum += __shfl_xor(sum, 4);
    sum += __shfl_xor(sum, 8);
    inv[r] = 1.f / sum;
  }
  int pbase = w * 16 * LP;
#pragma unroll
  for (int jt = 0; jt < L16; ++jt)
#pragma unroll
    for (int r = 0; r < 4; ++r)
      Ps[pbase + (q * 4 + r) * LP + jt * 16 + r15] = f2b(s[jt][r]);
  __syncthreads();
  f32x4 o[2] = {z, z};
#pragma unroll
  for (int kt = 0; kt < L / 32; ++kt) {
    bf16x8 ap = *(const bf16x8*)&Ps[pbase + r15 * LP + kt * 32 + q * 8];
#pragma unroll
    for (int nt = 0; nt < 2; ++nt) {
      bf16x8 bv = *(const bf16x8*)&VT[(nt * 16 + r15) * LP + kt * 32 + q * 8];
      o[nt] = __builtin_amdgcn_mfma_f32_16x16x32_bf16(ap, bv, o[nt], 0, 0, 0);
    }
  }
#pragma unroll
  for (int nt = 0; nt < 2; ++nt)
#pragma unroll
    for (int r = 0; r < 4; ++r) {
      float v = o[nt][r] * inv[r];
      size_t addr = ((size_t)(w * 16 + q * 4 + r) * Bt + t) * 256 + head * 32 + nt * 16 + r15;
      O[addr] = f2b(v);
    }
}

// ------- LN1: x = LN(src + src2_short[permuted]), one wave per token ----
__global__ void ln1(const float* __restrict__ src, const u16* __restrict__ s2b,
                    const float* __restrict__ g, const float* __restrict__ be,
                    u16* __restrict__ xln) {
  int gid = blockIdx.x * 256 + threadIdx.x;
  int u2 = gid >> 6, lane = gid & 63;
  int s = u2 >> 9, r = u2 & 511;
  int hq = s >> 3, wq = s & 7;
  int b = r >> 6, bh = (r >> 3) & 7, bw = r & 7;
  int n2 = hq * 512 + bh * 64 + wq * 8 + bw;
  size_t urow = (size_t)b * 8192 + n2;
  float4 a = ((const float4*)(src + urow * 256))[lane];
  uint2 vv = ((const uint2*)(s2b + (size_t)u2 * 256))[lane];
  float v0 = a.x + b2f((u16)(vv.x & 0xffff));
  float v1 = a.y + b2f((u16)(vv.x >> 16));
  float v2 = a.z + b2f((u16)(vv.y & 0xffff));
  float v3 = a.w + b2f((u16)(vv.y >> 16));
  float s1 = v0 + v1 + v2 + v3;
  float sq = v0*v0 + v1*v1 + v2*v2 + v3*v3;
#pragma unroll
  for (int off = 32; off >= 1; off >>= 1) {
    s1 += __shfl_xor(s1, off, 64);
    sq += __shfl_xor(sq, off, 64);
  }
  float mu = s1 * (1.f / 256.f);
  float var = sq * (1.f / 256.f) - mu * mu;
  float rstd = rsqrtf(var + 1e-5f);
  float4 g4 = ((const float4*)g)[lane];
  float4 e4 = ((const float4*)be)[lane];
  float y0 = (v0 - mu) * rstd * g4.x + e4.x;
  float y1 = (v1 - mu) * rstd * g4.y + e4.y;
  float y2 = (v2 - mu) * rstd * g4.z + e4.z;
  float y3 = (v3 - mu) * rstd * g4.w + e4.w;
  ((uint2*)(xln + urow * 256))[lane] = make_uint2(pack2(y0, y1), pack2(y2, y3));
}

// --- LN2 + final transposed write: out[b, c*8192 + n] = LN(x + ff)[b,n,c]
__global__ __launch_bounds__(256) void ln2t(const u16* __restrict__ ff, const u16* __restrict__ xln,
                                            const float* __restrict__ g, const float* __restrict__ be,
                                            float* __restrict__ out) {
  __shared__ u16 tileT[256][65];
  __shared__ float ps1[64][4];
  __shared__ float ps2[64][4];
  __shared__ float mu_s[64], rs_s[64];
  int b = blockIdx.x >> 7;
  int n0 = (blockIdx.x & 127) * 64;
  int tid = threadIdx.x;
  int i = tid >> 2, ch = tid & 3;
  size_t u = (size_t)b * 8192 + n0 + i;
  const uint4* fr = (const uint4*)(ff + u * 256 + ch * 64);
  const uint4* xr = (const uint4*)(xln + u * 256 + ch * 64);
  float s1 = 0.f, sq = 0.f;
#pragma unroll
  for (int j = 0; j < 8; ++j) {
    uint4 fv = fr[j];
    uint4 xv = xr[j];
    u32 fw[4] = {fv.x, fv.y, fv.z, fv.w};
    u32 xw[4] = {xv.x, xv.y, xv.z, xv.w};
    int cbase = ch * 64 + j * 8;
#pragma unroll
    for (int e = 0; e < 4; ++e) {
      float f0 = __uint_as_float(fw[e] << 16) + __uint_as_float(xw[e] << 16);
      float f1 = __uint_as_float(fw[e] & 0xffff0000u) + __uint_as_float(xw[e] & 0xffff0000u);
      s1 += f0 + f1; sq += f0 * f0 + f1 * f1;
      tileT[cbase + e * 2 + 0][i] = f2b(f0);
      tileT[cbase + e * 2 + 1][i] = f2b(f1);
    }
  }
  ps1[i][ch] = s1; ps2[i][ch] = sq;
  __syncthreads();
  if (tid < 64) {
    float a1 = ps1[tid][0] + ps1[tid][1] + ps1[tid][2] + ps1[tid][3];
    float a2 = ps2[tid][0] + ps2[tid][1] + ps2[tid][2] + ps2[tid][3];
    float mu = a1 * (1.f / 256.f);
    float var = a2 * (1.f / 256.f) - mu * mu;
    mu_s[tid] = mu;
    rs_s[tid] = rsqrtf(var + 1e-5f);
  }
  __syncthreads();
  int ii = tid & 63, cq = tid >> 6;
  float mu = mu_s[ii], rs = rs_s[ii];
  float* ob = out + (size_t)b * 2097152 + n0 + ii;
#pragma unroll 4
  for (int pass = 0; pass < 64; ++pass) {
    int c = pass * 4 + cq;
    float val = b2f(tileT[c][ii]);
    float y = (val - mu) * rs * g[c] + be[c];
    ob[(size_t)c * 8192] = y;
  }
}

extern "C" void kernel_launch(void* const* d_in, const int* in_sizes, int n_in,
                              void* d_out, int out_size, void* d_ws, size_t ws_size,
                              hipStream_t stream) {
  (void)in_sizes; (void)n_in; (void)out_size; (void)ws_size;
  const float* src = (const float*)d_in[0];
  const float* pos = (const float*)d_in[1];
  const float* wil = (const float*)d_in[2];
  const float* bil = (const float*)d_in[3];
  const float* wol = (const float*)d_in[4];
  const float* bol = (const float*)d_in[5];
  const float* wis = (const float*)d_in[6];
  const float* bis = (const float*)d_in[7];
  const float* wos = (const float*)d_in[8];
  const float* bos = (const float*)d_in[9];
  const float* w1  = (const float*)d_in[10];
  const float* b1  = (const float*)d_in[11];
  const float* w2  = (const float*)d_in[12];
  const float* b2  = (const float*)d_in[13];
  const float* g1  = (const float*)d_in[14];
  const float* be1 = (const float*)d_in[15];
  const float* g2  = (const float*)d_in[16];
  const float* be2 = (const float*)d_in[17];

  char* ws = (char*)d_ws;
  u16* WB   = (u16*)ws;                       // [0,2M): bf16 weights
  float* BS = (float*)(ws + (2ull << 20));    // scaled b_in copies
  u16* QKV  = (u16*)(ws + (4ull << 20));      // [4M,100M): qkv
  u16* R1   = (u16*)(ws + (100ull << 20));    // 32MB
  u16* R2   = (u16*)(ws + (132ull << 20));    // 32MB
  u16* R3   = (u16*)(ws + (164ull << 20));    // 32MB
  u16* H    = QKV;                            // 128MB hidden, spans QKV+R1

  u16* wl_in  = WB;
  u16* wl_out = WB + 196608;
  u16* ws_in  = WB + 262144;
  u16* ws_out = WB + 458752;
  u16* w1b    = WB + 524288;
  u16* w2b    = WB + 786432;
  float* bsl = BS;
  float* bss = BS + 768;

  prep_weights<<<1024, 256, 0, stream>>>(wil, wol, wis, wos, w1, w2, WB);
  prep_bias<<<6, 256, 0, stream>>>(bil, bis, BS);
  // long stage
  gather_long<<<16384, 256, 0, stream>>>(src, pos, R1, R2);
  gemm128<6><<<512 * 6, 256, 0, stream>>>(R1, R2, 512, wl_in, bsl, QKV, 768, 256, 0);
  attn_mfma<64, 1024><<<8192, 256, 0, stream>>>(QKV, R3);
  gemm128<2><<<512 * 2, 256, 0, stream>>>(R3, R3, 1 << 30, wl_out, bol, R1, 256, 256, 0);
  // short stage
  gather_short<<<16384, 256, 0, stream>>>(R1, pos, R2, R3);
  gemm128<6><<<512 * 6, 256, 0, stream>>>(R2, R3, 512, ws_in, bss, QKV, 768, 256, 0);
  attn_mfma<128, 512><<<4096, 512, 0, stream>>>(QKV, R1);
  gemm128<2><<<512 * 2, 256, 0, stream>>>(R1, R1, 1 << 30, ws_out, bos, R2, 256, 256, 0);
  // residual + LN1
  ln1<<<16384, 256, 0, stream>>>(src, R2, g1, be1, R3);
  // FFN
  gemm128<8><<<512 * 8, 256, 0, stream>>>(R3, R3, 1 << 30, w1b, b1, H, 1024, 256, 1);
  gemm128<2><<<512 * 2, 256, 0, stream>>>(H, H, 1 << 30, w2b, b2, R2, 256, 1024, 0);
  // residual + LN2 + transposed output
  ln2t<<<1024, 256, 0, stream>>>(R2, R3, g2, be2, (float*)d_out);
}